// Round 13
// baseline (259.810 us; speedup 1.0000x reference)
//
#include <hip/hip_runtime.h>
#include <hip/hip_bf16.h>
#include <stdint.h>

#define B_ 4
#define S_ 2048
#define H_ 1024
#define NH_ 16
#define HD_ 64

typedef __attribute__((ext_vector_type(8))) short short8;
typedef __attribute__((ext_vector_type(4))) float f32x4;
typedef __attribute__((ext_vector_type(4))) unsigned short ushort4v;

__device__ __forceinline__ unsigned short f2bf(float f) {
  union { float f; unsigned u; } x; x.f = f;
  unsigned r = x.u + 0x7fffu + ((x.u >> 16) & 1u);
  return (unsigned short)(r >> 16);
}

#define ALDS16(g, l) \
  __builtin_amdgcn_global_load_lds((const __attribute__((address_space(1))) void*)(g), \
                                   (__attribute__((address_space(3))) void*)(l), 16, 0, 0)

// ---------------- fused preprocessing: cvt_in + packmask + cvt_w ----------------
// blocks [0,12288): fp32->bf16 convert of q/k/v (4096 each)
// blocks [12288,14336): mask bit-pack (2048)
// blocks [14336,15360): weight transpose+convert (1024)
__global__ __launch_bounds__(256) void preproc(
    const float* __restrict__ q, const float* __restrict__ k, const float* __restrict__ v,
    const float* __restrict__ mask,
    const float* __restrict__ Wq, const float* __restrict__ Wk,
    const float* __restrict__ Wv, const float* __restrict__ Wo,
    unsigned short* __restrict__ oq, unsigned short* __restrict__ ok2,
    unsigned short* __restrict__ ov, unsigned long long* __restrict__ mb,
    unsigned short* __restrict__ wt) {
  __shared__ float tile[64][65];
  const int bid = blockIdx.x;
  const int t = threadIdx.x;
  if (bid < 12288) {
    const int z = bid >> 12;
    const int xb = bid & 4095;
    const float* src = z == 0 ? q : (z == 1 ? k : v);
    unsigned short* dst = z == 0 ? oq : (z == 1 ? ok2 : ov);
    const size_t i = ((size_t)xb * 256 + t) * 8;
    const f32x4 a = *reinterpret_cast<const f32x4*>(src + i);
    const f32x4 c = *reinterpret_cast<const f32x4*>(src + i + 4);
    short8 o;
#pragma unroll
    for (int j = 0; j < 4; ++j) { o[j] = (short)f2bf(a[j]); o[j + 4] = (short)f2bf(c[j]); }
    *reinterpret_cast<short8*>(dst + i) = o;
  } else if (bid < 14336) {
    const int pid = bid - 12288;
    const int w = t >> 6, lane = t & 63;
    const int wbase = (pid * 4 + w) * 32;
#pragma unroll 8
    for (int i = 0; i < 32; ++i) {
      const float vv = mask[(size_t)(wbase + i) * 64 + lane];
      const unsigned long long bits = __ballot(vv == 0.0f);
      if (lane == 0) mb[wbase + i] = bits;
    }
  } else {
    const int wid = bid - 14336;
    const int z = wid >> 8;
    const int yy = (wid >> 4) & 15, xx = wid & 15;
    const float* W = z == 0 ? Wq : (z == 1 ? Wk : (z == 2 ? Wv : Wo));
    unsigned short* out = wt + (size_t)z * H_ * H_;
    const int r0 = yy * 64, c0 = xx * 64;
    const int tr = t >> 4, tc = (t & 15) * 4;
#pragma unroll
    for (int rr = 0; rr < 4; ++rr) {
      const int row = rr * 16 + tr;
      const f32x4 val = *reinterpret_cast<const f32x4*>(W + (size_t)(r0 + row) * H_ + c0 + tc);
#pragma unroll
      for (int j = 0; j < 4; ++j) tile[row][tc + j] = val[j];
    }
    __syncthreads();
#pragma unroll
    for (int rr = 0; rr < 4; ++rr) {
      const int c = rr * 16 + tr;
      ushort4v o;
#pragma unroll
      for (int j = 0; j < 4; ++j) o[j] = f2bf(tile[tc + j][c]);
      *reinterpret_cast<ushort4v*>(out + (size_t)(c0 + c) * H_ + r0 + tc) = o;
    }
  }
}

// ---------------- GEMM body: C = (X @ Wt^T + bias) * oscale ----------------
// OUTMODE 0: bf16 head-split [B,NH,S,HD]. 1: fp32 flat [M,H]. 2: bf16 V-transposed.
template <int OUTMODE>
__device__ __forceinline__ void gemm_body(
    const unsigned short* __restrict__ X, const unsigned short* __restrict__ Wt,
    const float* __restrict__ bias, float oscale, unsigned short* __restrict__ obf,
    float* __restrict__ of32) {
  __shared__ unsigned short As[128 * 64];
  __shared__ unsigned short Bs[128 * 64];
  const int t = threadIdx.x;
  const int w = t >> 6, l = t & 63;
  const int lr = l & 15, lg = l >> 4;
  const int brow = blockIdx.x * 128, bcol = blockIdx.y * 128;
  const int wr = (w >> 1) * 64, wc = (w & 1) * 64;
  f32x4 acc[4][4] = {};
  const unsigned short* xb = X + (size_t)brow * 1024;
  const unsigned short* wb = Wt + (size_t)bcol * 1024;
  int srow[4], skl[4];
#pragma unroll
  for (int j = 0; j < 4; ++j) {
    const int c = t + j * 256;
    srow[j] = c >> 3;
    skl[j] = ((c & 7) ^ ((c >> 3) & 7)) * 8;
  }
  for (int kt = 0; kt < 1024; kt += 64) {
#pragma unroll
    for (int j = 0; j < 4; ++j) {
      ALDS16(xb + (size_t)srow[j] * 1024 + kt + skl[j], As + (t + j * 256) * 8);
      ALDS16(wb + (size_t)srow[j] * 1024 + kt + skl[j], Bs + (t + j * 256) * 8);
    }
    __syncthreads();
#pragma unroll
    for (int kk = 0; kk < 2; ++kk) {
      short8 af[4], bf[4];
#pragma unroll
      for (int m = 0; m < 4; ++m) {
        const int ra = wr + m * 16 + lr;
        af[m] = *reinterpret_cast<const short8*>(As + ra * 64 + ((kk * 4 + lg) ^ (ra & 7)) * 8);
      }
#pragma unroll
      for (int n = 0; n < 4; ++n) {
        const int rb = wc + n * 16 + lr;
        bf[n] = *reinterpret_cast<const short8*>(Bs + rb * 64 + ((kk * 4 + lg) ^ (rb & 7)) * 8);
      }
#pragma unroll
      for (int m = 0; m < 4; ++m)
#pragma unroll
        for (int n = 0; n < 4; ++n)
          acc[m][n] = __builtin_amdgcn_mfma_f32_16x16x32_bf16(af[m], bf[n], acc[m][n], 0, 0, 0);
    }
    __syncthreads();
  }
#pragma unroll
  for (int m = 0; m < 4; ++m) {
#pragma unroll
    for (int n = 0; n < 4; ++n) {
      const int gr0 = brow + wr + m * 16 + lg * 4;
      const int gc = bcol + wc + n * 16 + lr;
      if (OUTMODE == 2) {
        ushort4v o;
#pragma unroll
        for (int r = 0; r < 4; ++r) o[r] = f2bf((acc[m][n][r] + bias[gc]) * oscale);
        const int bb = gr0 >> 11, ss = gr0 & 2047, hh = gc >> 6, dd = gc & 63;
        *reinterpret_cast<ushort4v*>(obf + ((size_t)(bb * NH_ + hh) * HD_ + dd) * S_ + ss) = o;
      } else {
#pragma unroll
        for (int r = 0; r < 4; ++r) {
          const int gr = gr0 + r;
          const float val = (acc[m][n][r] + bias[gc]) * oscale;
          if (OUTMODE == 0) {
            const int bb = gr >> 11, ss = gr & 2047, hh = gc >> 6, dd = gc & 63;
            obf[(((size_t)(bb * NH_ + hh)) * S_ + ss) * HD_ + dd] = f2bf(val);
          } else {
            of32[(size_t)gr * H_ + gc] = val;
          }
        }
      }
    }
  }
}

// Q is pre-scaled by 0.125*log2(e) so attention can exp2() the raw MFMA output.
#define QSCL 0.1803368801111244f

// Fused Q/K/V projections via z-dim routing (one launch, 1536 blocks).
__global__ __launch_bounds__(256, 4) void gemm_qkv(
    const unsigned short* __restrict__ xq, const unsigned short* __restrict__ xk,
    const unsigned short* __restrict__ xv, const unsigned short* __restrict__ wt,
    const float* __restrict__ bq, const float* __restrict__ bk, const float* __restrict__ bv,
    unsigned short* __restrict__ qh, unsigned short* __restrict__ kh,
    unsigned short* __restrict__ vtv) {
  const int z = blockIdx.z;
  if (z == 0)      gemm_body<0>(xq, wt, bq, QSCL, qh, nullptr);
  else if (z == 1) gemm_body<0>(xk, wt + (size_t)H_ * H_, bk, 1.0f, kh, nullptr);
  else             gemm_body<2>(xv, wt + (size_t)2 * H_ * H_, bv, 1.0f, vtv, nullptr);
}

__global__ __launch_bounds__(256, 4) void gemm_out(
    const unsigned short* __restrict__ ao, const unsigned short* __restrict__ wt,
    const float* __restrict__ bo, float* __restrict__ out) {
  gemm_body<1>(ao, wt, bo, 1.0f, nullptr, out);
}

// ---------------- flash attention (r12 structure, best-known) ----------------
// 2048 blocks x 4 waves x 16 q-rows, 40 KB LDS, 4 blocks/CU; 4-heads/XCD
// residency (FETCH 28.8 MB verified r7-r12).
__global__ __launch_bounds__(256, 4) void attn_kernel(
    const unsigned short* __restrict__ qh, const unsigned short* __restrict__ kh,
    const unsigned short* __restrict__ vt, const unsigned long long* __restrict__ mb,
    unsigned short* __restrict__ ao) {
  __shared__ unsigned short Ks[2][64 * 64];
  __shared__ unsigned short Vs[2][64 * 64];
  __shared__ unsigned short Ps[4][16 * 64];
  const int t = threadIdx.x, w = t >> 6, l = t & 63;
  const int lr = l & 15, lg = l >> 4;
  const int flat = blockIdx.x;
  const int xcd = flat & 7;
  const int gen = flat >> 10;
  const int hh = (flat >> 8) & 3;
  const int qt = (flat >> 3) & 31;
  const int bh = gen * 32 + xcd * 4 + hh;
  const int b = bh >> 4, h = bh & 15;
  const unsigned short* qptr = qh + (size_t)bh * S_ * HD_;
  const unsigned short* kptr = kh + (size_t)bh * S_ * HD_;
  const unsigned short* vptr = vt + (size_t)bh * HD_ * S_;
  const unsigned long long* mbase = mb + (size_t)b * S_ * (S_ / 64);
  const int qbase = qt * 64 + w * 16;

  short8 qf[2];
  {
    const unsigned short* qp = qptr + (size_t)(qbase + lr) * HD_ + lg * 8;
    qf[0] = *reinterpret_cast<const short8*>(qp);
    qf[1] = *reinterpret_cast<const short8*>(qp + 32);
  }
  short8 ones;
#pragma unroll
  for (int jj = 0; jj < 8; ++jj) ones[jj] = (short)0x3F80;

  const int si0 = t, si1 = t + 256;
  const int srow0 = si0 >> 3, sk0 = ((si0 & 7) ^ (srow0 & 7)) * 8;
  const int srow1 = si1 >> 3, sk1 = ((si1 & 7) ^ (srow1 & 7)) * 8;
  const unsigned short* ksrc0 = kptr + (size_t)srow0 * HD_ + sk0;
  const unsigned short* ksrc1 = kptr + (size_t)srow1 * HD_ + sk1;
  const unsigned short* vsrc0 = vptr + (size_t)srow0 * S_ + sk0;
  const unsigned short* vsrc1 = vptr + (size_t)srow1 * S_ + sk1;
  size_t moff[4];
#pragma unroll
  for (int r = 0; r < 4; ++r)
    moff[r] = (size_t)(qbase + lg * 4 + r) * (S_ / 64);

  const int fragoff0 = lr * 64 + ((0 + lg) ^ (lr & 7)) * 8;
  const int fragoff1 = lr * 64 + ((4 + lg) ^ (lr & 7)) * 8;
  int pwoff[4][4];
#pragma unroll
  for (int r = 0; r < 4; ++r) {
    const int row = lg * 4 + r;
#pragma unroll
    for (int n = 0; n < 4; ++n) {
      const int col = n * 16 + lr;
      pwoff[r][n] = row * 64 + ((col >> 3) ^ (row & 7)) * 8 + (col & 7);
    }
  }

  ALDS16(ksrc0, Ks[0] + si0 * 8);
  ALDS16(ksrc1, Ks[0] + si1 * 8);
  ALDS16(vsrc0, Vs[0] + si0 * 8);
  ALDS16(vsrc1, Vs[0] + si1 * 8);
  __syncthreads();

  f32x4 acc_o[4] = {};
  f32x4 acc_l = {};
  unsigned short* pw = Ps[w];
  int cur = 0;

  for (int kv = 0; kv < S_; kv += 64) {
    unsigned msel[4][4];
#pragma unroll
    for (int r = 0; r < 4; ++r) {
      const unsigned long long mwv = mbase[moff[r] + (kv >> 6)];
      const unsigned long long sh = mwv >> lr;
      const unsigned lo = (unsigned)sh, hi = (unsigned)(sh >> 32);
      msel[r][0] = 0u - (lo & 1u);
      msel[r][1] = 0u - ((lo >> 16) & 1u);
      msel[r][2] = 0u - (hi & 1u);
      msel[r][3] = 0u - ((hi >> 16) & 1u);
    }

    const int nkv = (kv + 64 < S_) ? kv + 64 : 0;
    ALDS16(ksrc0 + (size_t)nkv * HD_, Ks[cur ^ 1] + si0 * 8);
    ALDS16(ksrc1 + (size_t)nkv * HD_, Ks[cur ^ 1] + si1 * 8);
    ALDS16(vsrc0 + nkv, Vs[cur ^ 1] + si0 * 8);
    ALDS16(vsrc1 + nkv, Vs[cur ^ 1] + si1 * 8);

    const unsigned short* Kf0 = Ks[cur] + fragoff0;
    const unsigned short* Kf1 = Ks[cur] + fragoff1;
    const unsigned short* Vf0 = Vs[cur] + fragoff0;
    const unsigned short* Vf1 = Vs[cur] + fragoff1;

    float p[4][4];
#pragma unroll
    for (int n = 0; n < 4; ++n) {
      const short8 kf0 = *reinterpret_cast<const short8*>(Kf0 + n * 1024);
      const short8 kf1 = *reinterpret_cast<const short8*>(Kf1 + n * 1024);
      f32x4 sc = {};
      sc = __builtin_amdgcn_mfma_f32_16x16x32_bf16(qf[0], kf0, sc, 0, 0, 0);
      sc = __builtin_amdgcn_mfma_f32_16x16x32_bf16(qf[1], kf1, sc, 0, 0, 0);
#pragma unroll
      for (int r = 0; r < 4; ++r) {
        union { float f; unsigned u; } cv;
        cv.f = __builtin_amdgcn_exp2f(sc[r]);
        cv.u &= msel[r][n];
        p[n][r] = cv.f;
      }
    }

#pragma unroll
    for (int r = 0; r < 4; ++r)
#pragma unroll
      for (int n = 0; n < 4; ++n) {
        union { float f; unsigned u; } cv; cv.f = p[n][r];
        pw[pwoff[r][n]] = (unsigned short)(cv.u >> 16);
      }
    short8 pf0 = *reinterpret_cast<const short8*>(pw + fragoff0);
    short8 pf1 = *reinterpret_cast<const short8*>(pw + fragoff1);
    acc_l = __builtin_amdgcn_mfma_f32_16x16x32_bf16(pf0, ones, acc_l, 0, 0, 0);
    acc_l = __builtin_amdgcn_mfma_f32_16x16x32_bf16(pf1, ones, acc_l, 0, 0, 0);

    __builtin_amdgcn_s_setprio(1);
#pragma unroll
    for (int d = 0; d < 4; ++d) {
      const short8 vf0 = *reinterpret_cast<const short8*>(Vf0 + d * 1024);
      const short8 vf1 = *reinterpret_cast<const short8*>(Vf1 + d * 1024);
      acc_o[d] = __builtin_amdgcn_mfma_f32_16x16x32_bf16(pf0, vf0, acc_o[d], 0, 0, 0);
      acc_o[d] = __builtin_amdgcn_mfma_f32_16x16x32_bf16(pf1, vf1, acc_o[d], 0, 0, 0);
    }
    __builtin_amdgcn_s_setprio(0);
    __syncthreads();
    cur ^= 1;
  }

#pragma unroll
  for (int r = 0; r < 4; ++r) {
    const float inv = __builtin_amdgcn_rcpf(acc_l[r]);
    const int qrow = qbase + lg * 4 + r;
    unsigned short* orow = ao + ((size_t)b * S_ + qrow) * H_ + h * HD_;
#pragma unroll
    for (int d = 0; d < 4; ++d)
      orow[d * 16 + lr] = f2bf(acc_o[d][r] * inv);
  }
}

extern "C" void kernel_launch(void* const* d_in, const int* in_sizes, int n_in,
                              void* d_out, int out_size, void* d_ws, size_t ws_size,
                              hipStream_t stream) {
  (void)in_sizes; (void)n_in; (void)out_size; (void)ws_size;
  const float* query = (const float*)d_in[0];
  const float* key_  = (const float*)d_in[1];
  const float* value = (const float*)d_in[2];
  const float* mask  = (const float*)d_in[3];
  const float* Wq = (const float*)d_in[4];
  const float* bq = (const float*)d_in[5];
  const float* Wk = (const float*)d_in[6];
  const float* bk = (const float*)d_in[7];
  const float* Wv = (const float*)d_in[8];
  const float* bv = (const float*)d_in[9];
  const float* Wo = (const float*)d_in[10];
  const float* bo = (const float*)d_in[11];
  float* out = (float*)d_out;

  char* ws = (char*)d_ws;
  const size_t MB16 = (size_t)1 << 24;
  unsigned short* XQ = (unsigned short*)(ws + 0 * MB16);
  unsigned short* XK = (unsigned short*)(ws + 1 * MB16);
  unsigned short* XV = (unsigned short*)(ws + 2 * MB16);
  unsigned short* QH = (unsigned short*)(ws + 3 * MB16);
  unsigned short* KH = (unsigned short*)(ws + 4 * MB16);
  unsigned short* VT = (unsigned short*)(ws + 5 * MB16);  // V written transposed
  unsigned short* WT = (unsigned short*)(ws + 6 * MB16);  // 8 MB
  unsigned long long* MBits = (unsigned long long*)(ws + 6 * MB16 + (size_t)4 * H_ * H_ * 2);  // 2 MB
  unsigned short* AO = XQ;  // reuse: XQ dead after gemm_qkv

  preproc<<<dim3(15360), 256, 0, stream>>>(query, key_, value, mask,
                                           Wq, Wk, Wv, Wo,
                                           XQ, XK, XV, MBits, WT);
  gemm_qkv<<<dim3(64, 8, 3), 256, 0, stream>>>(XQ, XK, XV, WT, bq, bk, bv, QH, KH, VT);
  attn_kernel<<<dim3(2048), 256, 0, stream>>>(QH, KH, VT, MBits, AO);
  gemm_out<<<dim3(64, 8), 256, 0, stream>>>(AO, WT + 3 * (size_t)H_ * H_, bo, out);
}